// Round 2
// baseline (402.089 us; speedup 1.0000x reference)
//
#include <hip/hip_runtime.h>
#include <hip/hip_bf16.h>
#include <math.h>

#define N 8192
#define FIN 256
#define D 64
#define ALPHA 0.2f
#define CS 2048            // columns per wave (4 waves cover N)

typedef __attribute__((ext_vector_type(8))) short bf16x8;
typedef __attribute__((ext_vector_type(4))) float f32x4;
typedef __attribute__((ext_vector_type(4))) int i32x4;

// ---------------- Kernel 1: h = x@trans (fp32), e1/e2 (fp32), hF fragment-order
__global__ __launch_bounds__(256) void k_h_e(
    const float* __restrict__ x, const float* __restrict__ trans,
    const float* __restrict__ attn,
    __hip_bfloat16* __restrict__ hF, float* __restrict__ e1, float* __restrict__ e2)
{
    __shared__ float xs[8 * FIN];
    __shared__ __hip_bfloat16 hl[8 * D];
    const int t = threadIdx.x;
    const int r0 = blockIdx.x * 8;

    #pragma unroll
    for (int v = 0; v < 2; ++v) {
        int idx = t + 256 * v;
        ((float4*)xs)[idx] = ((const float4*)(x + (size_t)r0 * FIN))[idx];
    }
    __syncthreads();

    const int lane = t & 63, w = t >> 6;
    const float* xa = xs + (2 * w) * FIN;
    const float* xb = xs + (2 * w + 1) * FIN;
    float acca = 0.f, accb = 0.f;
    #pragma unroll 8
    for (int k = 0; k < FIN; ++k) {
        const float tv = trans[k * D + lane];
        acca = fmaf(xa[k], tv, acca);
        accb = fmaf(xb[k], tv, accb);
    }
    const int ra = r0 + 2 * w, rb = ra + 1;

    const float a1 = attn[lane], a2 = attn[D + lane];
    float p1a = acca * a1, p2a = acca * a2;
    float p1b = accb * a1, p2b = accb * a2;
    #pragma unroll
    for (int mm = 1; mm <= 32; mm <<= 1) {
        p1a += __shfl_xor(p1a, mm);
        p2a += __shfl_xor(p2a, mm);
        p1b += __shfl_xor(p1b, mm);
        p2b += __shfl_xor(p2b, mm);
    }
    if (lane == 0) { e1[ra] = p1a; e2[ra] = p2a; e1[rb] = p1b; e2[rb] = p2b; }

    hl[(2 * w) * D + lane]     = __float2bfloat16(acca);
    hl[(2 * w + 1) * D + lane] = __float2bfloat16(accb);
    __syncthreads();
    if (t < D) {
        const int q = t >> 4, m = t & 15;
        const int cb = r0 >> 5, jgrp = (r0 >> 3) & 3;
        union { bf16x8 v; __hip_bfloat16 h[8]; } o;
        #pragma unroll
        for (int r = 0; r < 8; ++r) o.h[r] = hl[r * D + q * 16 + m];
        *(bf16x8*)(hF + (((size_t)cb * 4 + q) * 64 + jgrp * 16 + m) * 8) = o.v;
    }
}

// ---------------- Kernel 2: fully-fused masked softmax-attention ---------------
// Block owns 16 rows x ALL 8192 cols; wave w covers cols [2048w, 2048w+2048).
// R13: mask read DIRECTLY into registers (nt, streaming) -- each lane's per-iter
// mask need is a contiguous 32B (row i0+m, cols quad*8..+8 of the 32-col step),
// so two adjacent int4 loads coalesce to full 128B lines per row. Depth-4
// rolling prefetch (named slots, static indexing) keeps the mask stream always
// in flight -- no vmcnt(0) drain anywhere in the main loop. LDS holds ONLY the
// cross-wave combine (16.6 KB vs 66.8 KB before) -> 3 blocks/CU instead of 2.
// Numerics: identical op order (lsum, MFMA accum, w=0..3 combine) to previous
// version -> bit-identical output.
__global__ __launch_bounds__(256, 3) void k_attn(
    const int* __restrict__ mask, const __hip_bfloat16* __restrict__ hF,
    const float* __restrict__ e1, const float* __restrict__ e2,
    float* __restrict__ out)
{
    __shared__ float cw[4 * 16 * 64];   // [wave][row][col] fp32 combine, 16 KB
    __shared__ float lw[4][16];
    const int t = threadIdx.x;
    const int lane = t & 63, wave = t >> 6;
    const int i0 = blockIdx.x * 16;
    const int c0 = wave * CS;
    const int m = lane & 15, quad = lane >> 4;
    const int row = i0 + m;
    const float er = e1[row];

    const __hip_bfloat16* hfp = hF + (((size_t)(c0 >> 5)) * 4 * 64 + lane) * 8;
    const i32x4* mp = (const i32x4*)(mask + (size_t)row * N + c0 + quad * 8);
    const float* ep = e2 + c0 + quad * 8;

    f32x4 acc0 = {0.f, 0.f, 0.f, 0.f};
    f32x4 acc1 = {0.f, 0.f, 0.f, 0.f};
    f32x4 acc2 = {0.f, 0.f, 0.f, 0.f};
    f32x4 acc3 = {0.f, 0.f, 0.f, 0.f};
    float lsum = 0.f;

    // ---- depth-4 rolling mask prefetch: iter it uses mp[it*8], mp[it*8+1]
    i32x4 pmA0 = __builtin_nontemporal_load(mp + 0);
    i32x4 pmB0 = __builtin_nontemporal_load(mp + 1);
    i32x4 pmA1 = __builtin_nontemporal_load(mp + 8);
    i32x4 pmB1 = __builtin_nontemporal_load(mp + 9);
    i32x4 pmA2 = __builtin_nontemporal_load(mp + 16);
    i32x4 pmB2 = __builtin_nontemporal_load(mp + 17);
    i32x4 pmA3 = __builtin_nontemporal_load(mp + 24);
    i32x4 pmB3 = __builtin_nontemporal_load(mp + 25);

    // depth-1 hF/e2 prefetch (L2-resident, short latency)
    bf16x8 pb0 = *(const bf16x8*)(hfp);
    bf16x8 pb1 = *(const bf16x8*)(hfp + 512);
    bf16x8 pb2 = *(const bf16x8*)(hfp + 1024);
    bf16x8 pb3 = *(const bf16x8*)(hfp + 1536);
    float4 pea = *(const float4*)(ep);
    float4 peb = *(const float4*)(ep + 4);

#define ITER(J, IT, LASTC4)                                                    \
    {                                                                          \
        const i32x4 m0 = pmA##J, m1 = pmB##J;                                  \
        if (!(LASTC4)) {                                                       \
            pmA##J = __builtin_nontemporal_load(mp + ((IT) + 4) * 8);          \
            pmB##J = __builtin_nontemporal_load(mp + ((IT) + 4) * 8 + 1);      \
        }                                                                      \
        const bf16x8 b0 = pb0, b1 = pb1, b2 = pb2, b3 = pb3;                   \
        const float4 ea = pea, eb = peb;                                       \
        if ((IT) < 63) {                                                       \
            const size_t ito = (size_t)((IT) + 1) * 2048;                      \
            pb0 = *(const bf16x8*)(hfp + ito);                                 \
            pb1 = *(const bf16x8*)(hfp + ito + 512);                           \
            pb2 = *(const bf16x8*)(hfp + ito + 1024);                          \
            pb3 = *(const bf16x8*)(hfp + ito + 1536);                          \
            pea = *(const float4*)(ep + ((IT) + 1) * 32);                      \
            peb = *(const float4*)(ep + ((IT) + 1) * 32 + 4);                  \
        }                                                                      \
        float s0 = er + ea.x; s0 = s0 > 0.f ? s0 : ALPHA * s0;                 \
        float s1 = er + ea.y; s1 = s1 > 0.f ? s1 : ALPHA * s1;                 \
        float s2 = er + ea.z; s2 = s2 > 0.f ? s2 : ALPHA * s2;                 \
        float s3 = er + ea.w; s3 = s3 > 0.f ? s3 : ALPHA * s3;                 \
        float s4 = er + eb.x; s4 = s4 > 0.f ? s4 : ALPHA * s4;                 \
        float s5 = er + eb.y; s5 = s5 > 0.f ? s5 : ALPHA * s5;                 \
        float s6 = er + eb.z; s6 = s6 > 0.f ? s6 : ALPHA * s6;                 \
        float s7 = er + eb.w; s7 = s7 > 0.f ? s7 : ALPHA * s7;                 \
        const float p0 = m0[0] ? __expf(s0) : 0.f;                             \
        const float p1 = m0[1] ? __expf(s1) : 0.f;                             \
        const float p2 = m0[2] ? __expf(s2) : 0.f;                             \
        const float p3 = m0[3] ? __expf(s3) : 0.f;                             \
        const float p4 = m1[0] ? __expf(s4) : 0.f;                             \
        const float p5 = m1[1] ? __expf(s5) : 0.f;                             \
        const float p6 = m1[2] ? __expf(s6) : 0.f;                             \
        const float p7 = m1[3] ? __expf(s7) : 0.f;                             \
        union { bf16x8 v; __hip_bfloat162 h2[4]; } af;                         \
        af.h2[0] = __float22bfloat162_rn(make_float2(p0, p1));                 \
        af.h2[1] = __float22bfloat162_rn(make_float2(p2, p3));                 \
        af.h2[2] = __float22bfloat162_rn(make_float2(p4, p5));                 \
        af.h2[3] = __float22bfloat162_rn(make_float2(p6, p7));                 \
        lsum += ((p0 + p1) + (p2 + p3)) + ((p4 + p5) + (p6 + p7));             \
        acc0 = __builtin_amdgcn_mfma_f32_16x16x32_bf16(af.v, b0, acc0, 0, 0, 0); \
        acc1 = __builtin_amdgcn_mfma_f32_16x16x32_bf16(af.v, b1, acc1, 0, 0, 0); \
        acc2 = __builtin_amdgcn_mfma_f32_16x16x32_bf16(af.v, b2, acc2, 0, 0, 0); \
        acc3 = __builtin_amdgcn_mfma_f32_16x16x32_bf16(af.v, b3, acc3, 0, 0, 0); \
    }

    for (int c4 = 0; c4 < 16; ++c4) {
        const int base = c4 * 4;
        const bool lastc4 = (c4 == 15);
        ITER(0, base + 0, lastc4)
        ITER(1, base + 1, lastc4)
        ITER(2, base + 2, lastc4)
        ITER(3, base + 3, lastc4)
    }
#undef ITER

    // per-wave row sums: row m's columns live in lanes m, m+16, m+32, m+48
    lsum += __shfl_xor(lsum, 16);
    lsum += __shfl_xor(lsum, 32);
    if (quad == 0) lw[wave][m] = lsum;

    // ---- cross-wave combine in LDS ----
    #pragma unroll
    for (int reg = 0; reg < 4; ++reg) {
        float* rbase = cw + (wave * 16 + quad * 4 + reg) * 64;
        rbase[m     ] = acc0[reg];
        rbase[m + 16] = acc1[reg];
        rbase[m + 32] = acc2[reg];
        rbase[m + 48] = acc3[reg];
    }
    __syncthreads();
    #pragma unroll
    for (int rr = 0; rr < 4; ++rr) {
        const int idx = rr * 256 + t;          // 0..1023
        const int r = idx >> 6, c = idx & 63;
        // sum order w=0..3 == previous version -> identical numerics
        float s = ((cw[(0 * 16 + r) * 64 + c] + cw[(1 * 16 + r) * 64 + c])
                +   cw[(2 * 16 + r) * 64 + c]) + cw[(3 * 16 + r) * 64 + c];
        float l = ((lw[0][r] + lw[1][r]) + lw[2][r]) + lw[3][r];
        out[(size_t)(i0 + r) * D + c] = s / l;
    }
}

extern "C" void kernel_launch(void* const* d_in, const int* in_sizes, int n_in,
                              void* d_out, int out_size, void* d_ws, size_t ws_size,
                              hipStream_t stream) {
    const float* x     = (const float*)d_in[0];
    const int*   mask  = (const int*)d_in[1];
    const float* trans = (const float*)d_in[2];
    const float* attn  = (const float*)d_in[3];
    float* out = (float*)d_out;

    char* ws = (char*)d_ws;
    __hip_bfloat16* hF = (__hip_bfloat16*)ws;                 // 1 MB
    char* p = ws + (size_t)D * N * sizeof(__hip_bfloat16);
    float* e1 = (float*)p;            p += (size_t)N * sizeof(float);
    float* e2 = (float*)p;            p += (size_t)N * sizeof(float);

    k_h_e<<<N / 8, 256, 0, stream>>>(x, trans, attn, hF, e1, e2);
    k_attn<<<N / 16, 256, 0, stream>>>(mask, hF, e1, e2, out);
}

// Round 3
// 377.348 us; speedup vs baseline: 1.0656x; 1.0656x over previous
//
#include <hip/hip_runtime.h>
#include <hip/hip_bf16.h>
#include <math.h>

#define N 8192
#define FIN 256
#define D 64
#define ALPHA 0.2f
#define CS 2048            // columns per wave (4 waves cover N)
#define HBYTES 8192        // half-tile: 16 rows x 512 B (4 iters of 32 cols)

typedef __attribute__((ext_vector_type(8))) short bf16x8;
typedef __attribute__((ext_vector_type(4))) float f32x4;

// ---------------- Kernel 1: h = x@trans (fp32), e1/e2 (fp32), hF fragment-order
__global__ __launch_bounds__(256) void k_h_e(
    const float* __restrict__ x, const float* __restrict__ trans,
    const float* __restrict__ attn,
    __hip_bfloat16* __restrict__ hF, float* __restrict__ e1, float* __restrict__ e2)
{
    __shared__ float xs[8 * FIN];
    __shared__ __hip_bfloat16 hl[8 * D];
    const int t = threadIdx.x;
    const int r0 = blockIdx.x * 8;

    #pragma unroll
    for (int v = 0; v < 2; ++v) {
        int idx = t + 256 * v;
        ((float4*)xs)[idx] = ((const float4*)(x + (size_t)r0 * FIN))[idx];
    }
    __syncthreads();

    const int lane = t & 63, w = t >> 6;
    const float* xa = xs + (2 * w) * FIN;
    const float* xb = xs + (2 * w + 1) * FIN;
    float acca = 0.f, accb = 0.f;
    #pragma unroll 8
    for (int k = 0; k < FIN; ++k) {
        const float tv = trans[k * D + lane];
        acca = fmaf(xa[k], tv, acca);
        accb = fmaf(xb[k], tv, accb);
    }
    const int ra = r0 + 2 * w, rb = ra + 1;

    const float a1 = attn[lane], a2 = attn[D + lane];
    float p1a = acca * a1, p2a = acca * a2;
    float p1b = accb * a1, p2b = accb * a2;
    #pragma unroll
    for (int mm = 1; mm <= 32; mm <<= 1) {
        p1a += __shfl_xor(p1a, mm);
        p2a += __shfl_xor(p2a, mm);
        p1b += __shfl_xor(p1b, mm);
        p2b += __shfl_xor(p2b, mm);
    }
    if (lane == 0) { e1[ra] = p1a; e2[ra] = p2a; e1[rb] = p1b; e2[rb] = p2b; }

    hl[(2 * w) * D + lane]     = __float2bfloat16(acca);
    hl[(2 * w + 1) * D + lane] = __float2bfloat16(accb);
    __syncthreads();
    if (t < D) {
        const int q = t >> 4, m = t & 15;
        const int cb = r0 >> 5, jgrp = (r0 >> 3) & 3;
        union { bf16x8 v; __hip_bfloat16 h[8]; } o;
        #pragma unroll
        for (int r = 0; r < 8; ++r) o.h[r] = hl[r * D + q * 16 + m];
        *(bf16x8*)(hF + (((size_t)cb * 4 + q) * 64 + jgrp * 16 + m) * 8) = o.v;
    }
}

// stage one half-tile: 16 rows x 512 B.  8 DMA instrs; instr i stages rows
// 2i,2i+1 (lane L: row 2i+(L>>5), bytes (L&31)*16).  LDS dest contiguous 1 KB.
__device__ __forceinline__ void stage_half(const char* gs, char* ld) {
    #pragma unroll
    for (int i = 0; i < 8; ++i) {
        __builtin_amdgcn_global_load_lds(
            (const __attribute__((address_space(1))) void*)(gs + (size_t)i * (2u * N * 4u)),
            (__attribute__((address_space(3))) void*)(ld + i * 1024),
            16, 0, 2 /* nt */);
    }
}

// ---------------- Kernel 2: fully-fused masked softmax-attention ---------------
// Block owns 16 rows x ALL 8192 cols; wave w covers cols [2048w, 2048w+2048).
// R14: DMA staging kept (proven efficient) but DOUBLE-BUFFERED at half-tile
// granularity (4 iters = 16 rows x 512 B) with COUNTED vmcnt -- never vmcnt(0)
// in the main loop (T3/T4).  While half h computes, halves h+1,h+2 are in
// flight: vmcnt(14) retires exactly the oldest 8 DMAs (half h) while leaving
// half h+1's 8 DMAs + the 6 in-flight hF/e2 prefetch loads flying.  HBM never
// goes idle on the phase boundary.  Numerics: identical op order (lsum, MFMA
// accum, w=0..3 combine) to the 382.8 baseline -> bit-identical output.
__global__ __launch_bounds__(256) void k_attn(
    const int* __restrict__ mask, const __hip_bfloat16* __restrict__ hF,
    const float* __restrict__ e1, const float* __restrict__ e2,
    float* __restrict__ out)
{
    __shared__ __align__(16) char smem[4 * 2 * HBYTES];   // 64 KB (2 halves/wave)
    __shared__ float lw[4][16];
    const int t = threadIdx.x;
    const int lane = t & 63, wave = t >> 6;
    const int i0 = blockIdx.x * 16;
    const int c0 = wave * CS;
    const int m = lane & 15, quad = lane >> 4;
    const float er = e1[i0 + m];

    char* sw = smem + wave * (2 * HBYTES);
    // per-lane DMA source base: row i0+(lane>>5), col c0+(lane&31)*4
    const char* gdma = (const char*)(mask + (size_t)(i0 + (lane >> 5)) * N
                                          + c0 + (lane & 31) * 4);
    const int moff = m * 512 + quad * 32;   // reader offset within a half buffer

    const __hip_bfloat16* hfp = hF + (((size_t)(c0 >> 5)) * 4 * 64 + lane) * 8;
    const float* ep = e2 + c0 + quad * 8;

    f32x4 acc0 = {0.f, 0.f, 0.f, 0.f};
    f32x4 acc1 = {0.f, 0.f, 0.f, 0.f};
    f32x4 acc2 = {0.f, 0.f, 0.f, 0.f};
    f32x4 acc3 = {0.f, 0.f, 0.f, 0.f};
    float lsum = 0.f;

    // prologue: halves 0,1 in flight (16 DMAs)
    stage_half(gdma,        sw + lane * 16);
    stage_half(gdma + 512,  sw + HBYTES + lane * 16);

    // depth-1 hF/e2 prefetch (L2-resident, short latency)
    bf16x8 pb0 = *(const bf16x8*)(hfp);
    bf16x8 pb1 = *(const bf16x8*)(hfp + 512);
    bf16x8 pb2 = *(const bf16x8*)(hfp + 1024);
    bf16x8 pb3 = *(const bf16x8*)(hfp + 1536);
    float4 pea = *(const float4*)(ep);
    float4 peb = *(const float4*)(ep + 4);

#define ITER(P, ITN, PREF)                                                     \
    {                                                                          \
        const int4 mm0 = *(const int4*)(sb + moff + (P) * 128);                \
        const int4 mm1 = *(const int4*)(sb + moff + (P) * 128 + 16);           \
        const bf16x8 b0 = pb0, b1 = pb1, b2 = pb2, b3 = pb3;                   \
        const float4 ea = pea, eb = peb;                                       \
        if (PREF) {                                                            \
            const size_t ito = (size_t)((ITN) + 1) * 2048;                     \
            pb0 = *(const bf16x8*)(hfp + ito);                                 \
            pb1 = *(const bf16x8*)(hfp + ito + 512);                           \
            pb2 = *(const bf16x8*)(hfp + ito + 1024);                          \
            pb3 = *(const bf16x8*)(hfp + ito + 1536);                          \
            pea = *(const float4*)(ep + ((ITN) + 1) * 32);                     \
            peb = *(const float4*)(ep + ((ITN) + 1) * 32 + 4);                 \
        }                                                                      \
        float s0 = er + ea.x; s0 = s0 > 0.f ? s0 : ALPHA * s0;                 \
        float s1 = er + ea.y; s1 = s1 > 0.f ? s1 : ALPHA * s1;                 \
        float s2 = er + ea.z; s2 = s2 > 0.f ? s2 : ALPHA * s2;                 \
        float s3 = er + ea.w; s3 = s3 > 0.f ? s3 : ALPHA * s3;                 \
        float s4 = er + eb.x; s4 = s4 > 0.f ? s4 : ALPHA * s4;                 \
        float s5 = er + eb.y; s5 = s5 > 0.f ? s5 : ALPHA * s5;                 \
        float s6 = er + eb.z; s6 = s6 > 0.f ? s6 : ALPHA * s6;                 \
        float s7 = er + eb.w; s7 = s7 > 0.f ? s7 : ALPHA * s7;                 \
        const float p0 = mm0.x ? __expf(s0) : 0.f;                             \
        const float p1 = mm0.y ? __expf(s1) : 0.f;                             \
        const float p2 = mm0.z ? __expf(s2) : 0.f;                             \
        const float p3 = mm0.w ? __expf(s3) : 0.f;                             \
        const float p4 = mm1.x ? __expf(s4) : 0.f;                             \
        const float p5 = mm1.y ? __expf(s5) : 0.f;                             \
        const float p6 = mm1.z ? __expf(s6) : 0.f;                             \
        const float p7 = mm1.w ? __expf(s7) : 0.f;                             \
        union { bf16x8 v; __hip_bfloat162 h2[4]; } af;                         \
        af.h2[0] = __float22bfloat162_rn(make_float2(p0, p1));                 \
        af.h2[1] = __float22bfloat162_rn(make_float2(p2, p3));                 \
        af.h2[2] = __float22bfloat162_rn(make_float2(p4, p5));                 \
        af.h2[3] = __float22bfloat162_rn(make_float2(p6, p7));                 \
        lsum += ((p0 + p1) + (p2 + p3)) + ((p4 + p5) + (p6 + p7));             \
        acc0 = __builtin_amdgcn_mfma_f32_16x16x32_bf16(af.v, b0, acc0, 0, 0, 0); \
        acc1 = __builtin_amdgcn_mfma_f32_16x16x32_bf16(af.v, b1, acc1, 0, 0, 0); \
        acc2 = __builtin_amdgcn_mfma_f32_16x16x32_bf16(af.v, b2, acc2, 0, 0, 0); \
        acc3 = __builtin_amdgcn_mfma_f32_16x16x32_bf16(af.v, b3, acc3, 0, 0, 0); \
    }

    for (int h = 0; h < 15; ++h) {
        // retire oldest 8 outstanding VMEM ops (= half h's DMAs); half h+1's
        // 8 DMAs + up to 6 hF/e2 prefetch loads stay in flight.
        __builtin_amdgcn_s_waitcnt(0x0F7E);   // vmcnt(14)
        __builtin_amdgcn_sched_barrier(0);
        const char* sb = sw + (h & 1) * HBYTES;
        const int itb = h * 4;
        ITER(0, itb + 0, true)
        ITER(1, itb + 1, true)
        ITER(2, itb + 2, true)
        ITER(3, itb + 3, true)
        if (h < 14)   // stage half h+2 into the buffer half h just vacated
            stage_half(gdma + (size_t)(h + 2) * 512,
                       sw + (h & 1) * HBYTES + lane * 16);
    }
    {   // tail: half 15 (only its 8 DMAs + <=6 prefetch loads can be out)
        __builtin_amdgcn_s_waitcnt(0x0F76);   // vmcnt(6)
        __builtin_amdgcn_sched_barrier(0);
        const char* sb = sw + HBYTES;
        ITER(0, 60, true)
        ITER(1, 61, true)
        ITER(2, 62, true)
        ITER(3, 63, false)
    }
#undef ITER

    // per-wave row sums: row m's columns live in lanes m, m+16, m+32, m+48
    lsum += __shfl_xor(lsum, 16);
    lsum += __shfl_xor(lsum, 32);
    if (quad == 0) lw[wave][m] = lsum;

    // ---- cross-wave combine in LDS (alias over dead mask buffers) ----
    __syncthreads();   // all DMAs retired (vmcnt waits above); buffers dead
    float* cw = (float*)smem;   // [wave][row][col] = [4][16][64] fp32, 16 KB
    #pragma unroll
    for (int reg = 0; reg < 4; ++reg) {
        float* rbase = cw + (wave * 16 + quad * 4 + reg) * 64;
        rbase[m     ] = acc0[reg];
        rbase[m + 16] = acc1[reg];
        rbase[m + 32] = acc2[reg];
        rbase[m + 48] = acc3[reg];
    }
    __syncthreads();
    #pragma unroll
    for (int rr = 0; rr < 4; ++rr) {
        const int idx = rr * 256 + t;          // 0..1023
        const int r = idx >> 6, c = idx & 63;
        // sum order w=0..3 == baseline -> identical numerics
        float s = ((cw[(0 * 16 + r) * 64 + c] + cw[(1 * 16 + r) * 64 + c])
                +   cw[(2 * 16 + r) * 64 + c]) + cw[(3 * 16 + r) * 64 + c];
        float l = ((lw[0][r] + lw[1][r]) + lw[2][r]) + lw[3][r];
        out[(size_t)(i0 + r) * D + c] = s / l;
    }
}

extern "C" void kernel_launch(void* const* d_in, const int* in_sizes, int n_in,
                              void* d_out, int out_size, void* d_ws, size_t ws_size,
                              hipStream_t stream) {
    const float* x     = (const float*)d_in[0];
    const int*   mask  = (const int*)d_in[1];
    const float* trans = (const float*)d_in[2];
    const float* attn  = (const float*)d_in[3];
    float* out = (float*)d_out;

    char* ws = (char*)d_ws;
    __hip_bfloat16* hF = (__hip_bfloat16*)ws;                 // 1 MB
    char* p = ws + (size_t)D * N * sizeof(__hip_bfloat16);
    float* e1 = (float*)p;            p += (size_t)N * sizeof(float);
    float* e2 = (float*)p;            p += (size_t)N * sizeof(float);

    k_h_e<<<N / 8, 256, 0, stream>>>(x, trans, attn, hF, e1, e2);
    k_attn<<<N / 16, 256, 0, stream>>>(mask, hF, e1, e2, out);
}